// Round 10
// baseline (220.927 us; speedup 1.0000x reference)
//
#include <hip/hip_runtime.h>
#include <stdint.h>

#define S_LEN 2048
#define NH 12
#define DM 768
#define DK 64
#define NB 2
#define MROWS (NB * S_LEN)  // 4096

typedef __attribute__((ext_vector_type(8))) short short8;
typedef __attribute__((ext_vector_type(4))) float f32x4;
typedef __attribute__((ext_vector_type(4))) uint32_t u32x4;

__device__ __forceinline__ unsigned short bf16rne(float f) {
    union { float f; uint32_t u; } v; v.f = f;
    return (unsigned short)((v.u + 0x7FFFu + ((v.u >> 16) & 1u)) >> 16);
}

__device__ __forceinline__ uint32_t cvtpk(float lo, float hi) {
    uint32_t r;
    asm("v_cvt_pk_bf16_f32 %0, %1, %2" : "=v"(r) : "v"(lo), "v"(hi));
    return r;
}

// ---------------- prep: tiled LDS weight transpose + mask bit-pack ----------------
__global__ __launch_bounds__(256) void prep_kernel(
        const float* __restrict__ Wq, const float* __restrict__ Wk,
        const float* __restrict__ Wv, const float* __restrict__ Wo,
        const int* __restrict__ mask,
        unsigned short* __restrict__ WqT, unsigned short* __restrict__ WkT,
        unsigned short* __restrict__ WvT, unsigned short* __restrict__ WoT,
        uint32_t* __restrict__ pm) {
    const int bx = blockIdx.x, tid = threadIdx.x;
    if (bx < 576) {
        __shared__ __align__(16) unsigned short L[64 * 72];
        int kd0, n0;
        unsigned short* WT;
        if (bx < 432) {
            int which = bx / 144;
            int t2 = bx % 144;
            int h = t2 / 12; kd0 = (t2 % 12) * 64; n0 = h * 64;
            const float* W = (which == 0) ? Wq : (which == 1) ? Wk : Wv;
            WT = (which == 0) ? WqT : (which == 1) ? WkT : WvT;
            const int r = tid >> 2, c0 = (tid & 3) << 4;
            const size_t roff = ((size_t)(h * 768 + kd0 + r)) * 64 + c0;
            float4 f[4];
#pragma unroll
            for (int i = 0; i < 4; ++i) f[i] = *(const float4*)(W + roff + i * 4);
            const float scl = (which == 0) ? 0.18033688011112042f : 1.0f;
#pragma unroll
            for (int i = 0; i < 4; ++i) {
                L[(c0 + i * 4 + 0) * 72 + r] = bf16rne(f[i].x * scl);
                L[(c0 + i * 4 + 1) * 72 + r] = bf16rne(f[i].y * scl);
                L[(c0 + i * 4 + 2) * 72 + r] = bf16rne(f[i].z * scl);
                L[(c0 + i * 4 + 3) * 72 + r] = bf16rne(f[i].w * scl);
            }
        } else {
            int t3 = bx - 432;
            kd0 = (t3 / 12) * 64; n0 = (t3 % 12) * 64;
            WT = WoT;
            const int r = tid >> 2, c0 = (tid & 3) << 4;
            const size_t roff = ((size_t)(kd0 + r)) * 768 + n0 + c0;
            float4 f[4];
#pragma unroll
            for (int i = 0; i < 4; ++i) f[i] = *(const float4*)(Wo + roff + i * 4);
#pragma unroll
            for (int i = 0; i < 4; ++i) {
                L[(c0 + i * 4 + 0) * 72 + r] = bf16rne(f[i].x);
                L[(c0 + i * 4 + 1) * 72 + r] = bf16rne(f[i].y);
                L[(c0 + i * 4 + 2) * 72 + r] = bf16rne(f[i].z);
                L[(c0 + i * 4 + 3) * 72 + r] = bf16rne(f[i].w);
            }
        }
        __syncthreads();
        const int nl = tid >> 2, cc = (tid & 3) << 4;
        short8 v0 = *(const short8*)&L[nl * 72 + cc];
        short8 v1 = *(const short8*)&L[nl * 72 + cc + 8];
        *(short8*)&WT[(size_t)(n0 + nl) * DM + kd0 + cc] = v0;
        *(short8*)&WT[(size_t)(n0 + nl) * DM + kd0 + cc + 8] = v1;
    } else {
        int t = (bx - 576) * 256 + tid;  // 1,048,576 threads
        const int4* mp = (const int4*)mask;
        int4 a = mp[2 * t], b = mp[2 * t + 1];
        unsigned int by =
            (a.x != 0 ? 1u : 0u)  | (a.y != 0 ? 2u : 0u)  | (a.z != 0 ? 4u : 0u)  | (a.w != 0 ? 8u : 0u) |
            (b.x != 0 ? 16u : 0u) | (b.y != 0 ? 32u : 0u) | (b.z != 0 ? 64u : 0u) | (b.w != 0 ? 128u : 0u);
        ((unsigned char*)pm)[t] = (unsigned char)by;
    }
}

// ---------------- projections: 64x128 tiles, grid 1152 (4.5 blocks/CU), R4-proven staging ----------------
// q,k -> [M, H*64] bf16 ; v -> vhT[b,h,d,s'] bf16 (key bit-permuted within 64-groups).
// A-stage: thread t -> row t>>2, 8 fp32 -> cvtpk -> one contiguous u32x4 (wave writes 1024B linear).
// B-stage: 2 global_load_lds per wave. 2 barriers/K-step; barrier drains cross-hidden by ~4.5 blocks/CU.
__global__ __launch_bounds__(256) void proj_gemm(
        const float* __restrict__ qf32, const float* __restrict__ kf32,
        const float* __restrict__ vf32,
        const unsigned short* __restrict__ WqT, const unsigned short* __restrict__ WkT,
        const unsigned short* __restrict__ WvT,
        unsigned short* __restrict__ qh, unsigned short* __restrict__ kh,
        unsigned short* __restrict__ vhT) {
    __shared__ __align__(16) unsigned short As[64 * 32];    // 4 KB
    __shared__ __align__(16) unsigned short Bs[128 * 32];   // 8 KB
    const int bid = blockIdx.x;
    const int xcd = bid & 7, pos = bid >> 3;      // 144 per XCD
    const int widx = xcd * 144 + pos;
    const int oi = widx / 6, by = widx % 6;       // oi 0..191
    const int z = oi >> 6, bx = oi & 63;
    const float* A = (z == 0) ? qf32 : (z == 1) ? kf32 : vf32;
    const unsigned short* BT = (z == 0) ? WqT : (z == 1) ? WkT : WvT;
    const int tid = threadIdx.x;
    const int lane = tid & 63, wid = tid >> 6;
    const int ww = wid & 1, wh = wid >> 1;
    const int quad = lane >> 4, l16 = lane & 15;
    const int lr = lane >> 2, lc = (lane & 3) * 8;
    typedef __attribute__((address_space(1))) const unsigned int* gp1;
    typedef __attribute__((address_space(3))) unsigned int* lp3;
    // A staging: thread t stages row t>>2 (64 rows), 8 fp32 at col (t&3)*8
    const int ar = tid >> 2, ac = (tid & 3) * 8;
    const float* Ag = A + (size_t)(bx * 64 + ar) * DM + ac;
    const int aoff = ar * 32 + ac;
    // B staging: wave wid stages rows wid*32 .. +32 via 2 gload_lds
    const unsigned short* Bg = BT + (size_t)(by * 128 + wid * 32 + lr) * DM + lc;
    unsigned short* Bl = &Bs[wid * 32 * 32];

    f32x4 acc[2][4] = {};
    for (int kt = 0; kt < DM; kt += 32) {
        __syncthreads();
        __builtin_amdgcn_global_load_lds((gp1)(const void*)(Bg + kt),           (lp3)(void*)Bl,             16, 0, 0);
        __builtin_amdgcn_global_load_lds((gp1)(const void*)(Bg + 16 * DM + kt), (lp3)(void*)(Bl + 16 * 32), 16, 0, 0);
        float4 x0 = *(const float4*)(Ag + kt), x1 = *(const float4*)(Ag + kt + 4);
        u32x4 ua;
        ua[0] = cvtpk(x0.x, x0.y); ua[1] = cvtpk(x0.z, x0.w);
        ua[2] = cvtpk(x1.x, x1.y); ua[3] = cvtpk(x1.z, x1.w);
        *(u32x4*)&As[aoff] = ua;
        __syncthreads();
        short8 af[2], bf[4];
#pragma unroll
        for (int i = 0; i < 2; ++i) af[i] = *(const short8*)&As[(wh * 32 + i * 16 + l16) * 32 + quad * 8];
#pragma unroll
        for (int j = 0; j < 4; ++j) bf[j] = *(const short8*)&Bs[(ww * 64 + j * 16 + l16) * 32 + quad * 8];
#pragma unroll
        for (int i = 0; i < 2; ++i)
#pragma unroll
            for (int j = 0; j < 4; ++j)
                acc[i][j] = __builtin_amdgcn_mfma_f32_16x16x32_bf16(af[i], bf[j], acc[i][j], 0, 0, 0);
    }

    const int row0 = bx * 64 + wh * 32;
    const int col0 = by * 128 + ww * 64;
    if (z < 2) {
        unsigned short* C = z ? kh : qh;
#pragma unroll
        for (int i = 0; i < 2; ++i)
#pragma unroll
            for (int j = 0; j < 4; ++j)
#pragma unroll
                for (int r = 0; r < 4; ++r)
                    C[(size_t)(row0 + i * 16 + quad * 4 + r) * DM + col0 + j * 16 + l16] = bf16rne(acc[i][j][r]);
    } else {
#pragma unroll
        for (int i = 0; i < 2; ++i)
#pragma unroll
            for (int j = 0; j < 4; ++j) {
                int row = row0 + i * 16 + quad * 4;  // = b*2048 + s, 4 consecutive s
                int col = col0 + j * 16 + l16;       // = h*64 + d
                int bb = row >> 11, s = row & 2047;
                int hh = col >> 6, d = col & 63;
                // key bit-permute within 64-group (preserves low 2 bits -> uint2 write contiguous)
                int g = (s >> 2) & 15;
                int pg = (g & 8) | ((g & 3) << 1) | ((g & 4) >> 2);
                int sp = (s & ~63) | (pg << 2) | (s & 3);
                uint32_t lo = (uint32_t)bf16rne(acc[i][j][0]) | ((uint32_t)bf16rne(acc[i][j][1]) << 16);
                uint32_t hi = (uint32_t)bf16rne(acc[i][j][2]) | ((uint32_t)bf16rne(acc[i][j][3]) << 16);
                uint2 o = make_uint2(lo, hi);
                *(uint2*)&vhT[(size_t)((bb * NH + hh) * DK + d) * S_LEN + sp] = o;
            }
    }
}

// ---------------- flash attention: K-split 4, XCD-swizzled, dbuf LDS (1 barrier/tile) ----------------
__global__ __launch_bounds__(256) void attn_kernel(
        const unsigned short* __restrict__ qh, const unsigned short* __restrict__ kh,
        const unsigned short* __restrict__ vhT, const uint32_t* __restrict__ pm,
        unsigned short* __restrict__ pob, float* __restrict__ lsb) {
    const int bid = blockIdx.x;
    const int xcd = bid & 7, pos = bid >> 3;
    const int wkr = xcd * 192 + pos;
    const int qt = wkr & 15;
    const int hz = wkr >> 4;       // 0..95
    const int h = hz % 12;
    const int z = hz / 12;         // 0..7 = b*4 + ks
    const int b = z >> 2, ks = z & 3;
    const int tid = threadIdx.x, w = tid >> 6, lane = tid & 63;
    const int quad = lane >> 4, l16 = lane & 15;
    __shared__ __align__(16) unsigned short SMEM[2 * 2 * 64 * 64];  // dbuf x (Ks|Vs), 32 KiB

    const int qrow0 = qt * 128 + w * 32;
    short8 qf[2][2];
#pragma unroll
    for (int mi = 0; mi < 2; ++mi) {
        const size_t qbase = (size_t)(b * S_LEN + qrow0 + mi * 16 + l16) * DM + h * DK;
        qf[mi][0] = *(const short8*)&qh[qbase + quad * 8];
        qf[mi][1] = *(const short8*)&qh[qbase + 32 + quad * 8];
    }
    short8 of = {};
    if (l16 == 0) {
#pragma unroll
        for (int j = 0; j < 8; ++j) of[j] = (short)0x3F80;
    }

    f32x4 out_t[2][4] = {};  // [mi][c2]: C[d][q], d = c2*16 + quad*4 + r, q = l16
    f32x4 outl[2] = {};

    const int srow = tid >> 2, scol = (tid & 3) << 4;
    const int ssw = (srow & 7) << 3;
    const int sc0 = srow * 64 + (scol ^ ssw);
    const int sc1 = srow * 64 + ((scol + 8) ^ ssw);
    const unsigned short* Kg = kh + (size_t)b * S_LEN * DM + h * DK;
    const unsigned short* Vg = vhT + (size_t)((b * NH + h) * DK) * S_LEN;
    const int kt0 = ks * (S_LEN / 4);
    const int NT = (S_LEN / 4) / 64;  // 8 tiles

    {
        short8 a0 = *(const short8*)&Kg[(size_t)(kt0 + srow) * DM + scol];
        short8 a1 = *(const short8*)&Kg[(size_t)(kt0 + srow) * DM + scol + 8];
        short8 a2 = *(const short8*)&Vg[(size_t)srow * S_LEN + kt0 + scol];
        short8 a3 = *(const short8*)&Vg[(size_t)srow * S_LEN + kt0 + scol + 8];
        *(short8*)&SMEM[sc0] = a0;
        *(short8*)&SMEM[sc1] = a1;
        *(short8*)&SMEM[4096 + sc0] = a2;
        *(short8*)&SMEM[4096 + sc1] = a3;
    }
    __syncthreads();

    int cur = 0;
    for (int t = 0; t < NT; ++t) {
        const int kt = kt0 + t * 64;
        const bool more = (t + 1 < NT);
        short8 kr0, kr1, vr0, vr1;
        if (more) {
            const int kn = kt + 64;
            kr0 = *(const short8*)&Kg[(size_t)(kn + srow) * DM + scol];
            kr1 = *(const short8*)&Kg[(size_t)(kn + srow) * DM + scol + 8];
            vr0 = *(const short8*)&Vg[(size_t)srow * S_LEN + kn + scol];
            vr1 = *(const short8*)&Vg[(size_t)srow * S_LEN + kn + scol + 8];
        }
        uint2 mw[2];
#pragma unroll
        for (int mi = 0; mi < 2; ++mi)
            mw[mi] = *(const uint2*)&pm[(size_t)(b * S_LEN + qrow0 + mi * 16 + l16) * 64 + (kt >> 5)];

        const unsigned short* Ks = SMEM + cur * 8192;
        const unsigned short* Vs = Ks + 4096;

        u32x4 pf32[2][2];
#pragma unroll
        for (int cb = 0; cb < 4; ++cb) {
            const int krw = cb * 16 + l16, ksw = (krw & 7) << 3;
            short8 kf0 = *(const short8*)&Ks[krw * 64 + ((quad * 8) ^ ksw)];
            short8 kf1 = *(const short8*)&Ks[krw * 64 + ((32 + quad * 8) ^ ksw)];
#pragma unroll
            for (int mi = 0; mi < 2; ++mi) {
                f32x4 zz = {0.f, 0.f, 0.f, 0.f};
                zz = __builtin_amdgcn_mfma_f32_16x16x32_bf16(kf0, qf[mi][0], zz, 0, 0, 0);
                zz = __builtin_amdgcn_mfma_f32_16x16x32_bf16(kf1, qf[mi][1], zz, 0, 0, 0);
                uint32_t mword = (cb & 2) ? mw[mi].y : mw[mi].x;
                float e[4];
#pragma unroll
                for (int r = 0; r < 4; ++r) {
                    float ev = __builtin_amdgcn_exp2f(zz[r]);
                    int32_t mneg = __builtin_amdgcn_sbfe((int32_t)mword, ((cb & 1) << 4) + quad * 4 + r, 1);
                    e[r] = __uint_as_float(__float_as_uint(ev) & (uint32_t)mneg);
                }
                pf32[mi][cb >> 1][(cb & 1) * 2 + 0] = cvtpk(e[0], e[1]);
                pf32[mi][cb >> 1][(cb & 1) * 2 + 1] = cvtpk(e[2], e[3]);
            }
        }
        short8 pf[2][2];
#pragma unroll
        for (int mi = 0; mi < 2; ++mi) {
            pf[mi][0] = __builtin_bit_cast(short8, pf32[mi][0]);
            pf[mi][1] = __builtin_bit_cast(short8, pf32[mi][1]);
        }

        __builtin_amdgcn_s_setprio(1);
#pragma unroll
        for (int c2 = 0; c2 < 4; ++c2) {
            const int vrw = c2 * 16 + l16, vsw = (vrw & 7) << 3;
            short8 vf0 = *(const short8*)&Vs[vrw * 64 + ((quad * 8) ^ vsw)];
            short8 vf1 = *(const short8*)&Vs[vrw * 64 + ((32 + quad * 8) ^ vsw)];
#pragma unroll
            for (int mi = 0; mi < 2; ++mi) {
                out_t[mi][c2] = __builtin_amdgcn_mfma_f32_16x16x32_bf16(vf0, pf[mi][0], out_t[mi][c2], 0, 0, 0);
                out_t[mi][c2] = __builtin_amdgcn_mfma_f32_16x16x32_bf16(vf1, pf[mi][1], out_t[mi][c2], 0, 0, 0);
            }
        }
#pragma unroll
        for (int mi = 0; mi < 2; ++mi) {
            outl[mi] = __builtin_amdgcn_mfma_f32_16x16x32_bf16(of, pf[mi][0], outl[mi], 0, 0, 0);
            outl[mi] = __builtin_amdgcn_mfma_f32_16x16x32_bf16(of, pf[mi][1], outl[mi], 0, 0, 0);
        }
        __builtin_amdgcn_s_setprio(0);

        if (more) {
            unsigned short* Kn = SMEM + (cur ^ 1) * 8192;
            *(short8*)&Kn[sc0] = kr0;
            *(short8*)&Kn[sc1] = kr1;
            *(short8*)&Kn[4096 + sc0] = vr0;
            *(short8*)&Kn[4096 + sc1] = vr1;
            __syncthreads();
            cur ^= 1;
        }
    }

    const int pz = z;
    if (quad == 0) {
#pragma unroll
        for (int mi = 0; mi < 2; ++mi)
            lsb[((size_t)pz * NH + h) * S_LEN + qrow0 + mi * 16 + l16] = outl[mi][0];
    }

    __syncthreads();
    unsigned short* Os = SMEM + w * 2048;
#pragma unroll
    for (int mi = 0; mi < 2; ++mi) {
        const int orow = mi * 16 + l16, osw = (orow & 7) << 3;
#pragma unroll
        for (int c2 = 0; c2 < 4; ++c2) {
            uint2 pw2;
            pw2.x = cvtpk(out_t[mi][c2][0], out_t[mi][c2][1]);
            pw2.y = cvtpk(out_t[mi][c2][2], out_t[mi][c2][3]);
            *(uint2*)&Os[orow * 64 + ((c2 * 16 + quad * 4) ^ osw)] = pw2;
        }
    }
    const int ql = lane >> 1, hf = lane & 1;
    const int qsw = (ql & 7) << 3;
    const int qg = qrow0 + ql;
    const size_t orowg = ((size_t)pz * S_LEN + qg) * DM + h * DK + hf * 32;
#pragma unroll
    for (int k2 = 0; k2 < 4; ++k2)
        *(short8*)&pob[orowg + k2 * 8] = *(const short8*)&Os[ql * 64 + ((hf * 32 + k2 * 8) ^ qsw)];
}

// ---------------- merge the four K-chunk partials -> ao bf16 ----------------
__global__ __launch_bounds__(256) void merge_kernel(const unsigned short* __restrict__ pob,
                                                    const float* __restrict__ lsb,
                                                    unsigned short* __restrict__ ao) {
    int t = blockIdx.x * 256 + threadIdx.x;   // 786432 threads, 4 elems each
    int sg = t / 192;                          // b*S + s
    int c = (t - sg * 192) * 4;                // col in [0,768)
    int b = sg >> 11, s = sg & 2047, h = c >> 6;
    float l = 0.f;
#pragma unroll
    for (int ksp = 0; ksp < 4; ++ksp)
        l += lsb[((size_t)(b * 4 + ksp) * NH + h) * S_LEN + s];
    float rl = 1.f / fmaxf(l, 1e-37f);
    float f0 = 0.f, f1 = 0.f, f2 = 0.f, f3 = 0.f;
#pragma unroll
    for (int ksp = 0; ksp < 4; ++ksp) {
        uint2 a = *(const uint2*)&pob[((size_t)((b * 4 + ksp) * S_LEN) + s) * DM + c];
        f0 += __uint_as_float(a.x << 16);
        f1 += __uint_as_float(a.x & 0xFFFF0000u);
        f2 += __uint_as_float(a.y << 16);
        f3 += __uint_as_float(a.y & 0xFFFF0000u);
    }
    uint32_t lo = cvtpk(f0 * rl, f1 * rl);
    uint32_t hi = cvtpk(f2 * rl, f3 * rl);
    *(uint2*)&ao[(size_t)sg * DM + c] = make_uint2(lo, hi);
}

// ---------------- output projection: 64x64 tiles, grid 768 (3 blocks/CU), dbuf 1-barrier ----------------
__global__ __launch_bounds__(256) void out_gemm(
        const unsigned short* __restrict__ ao, const unsigned short* __restrict__ WoT,
        float* __restrict__ C) {
    __shared__ __align__(16) unsigned short As[2][64 * 32];
    __shared__ __align__(16) unsigned short Bs[2][64 * 32];
    const int bid = blockIdx.x;
    const int xcd = bid & 7, pos = bid >> 3;   // 96 per XCD
    const int widx = xcd * 96 + pos;
    const int bx = widx / 12, by = widx % 12;  // bx 0..63, by 0..11
    const int tid = threadIdx.x;
    const int lane = tid & 63, wid = tid >> 6;
    const int ww = wid & 1, wh = wid >> 1;
    const int quad = lane >> 4, l16 = lane & 15;
    const int lr = lane >> 2, lc = (lane & 3) * 8;
    typedef __attribute__((address_space(1))) const unsigned int* gp1;
    typedef __attribute__((address_space(3))) unsigned int* lp3;
    const unsigned short* Ag = ao  + (size_t)(bx * 64 + wid * 16 + lr) * DM + lc;
    const unsigned short* Bg = WoT + (size_t)(by * 64 + wid * 16 + lr) * DM + lc;
    const int soff = wid * 16 * 32;
    f32x4 acc[2][2] = {};
    __builtin_amdgcn_global_load_lds((gp1)(const void*)Ag, (lp3)(void*)&As[0][soff], 16, 0, 0);
    __builtin_amdgcn_global_load_lds((gp1)(const void*)Bg, (lp3)(void*)&Bs[0][soff], 16, 0, 0);
    __syncthreads();
    int cur = 0;
    for (int kt = 0; kt < DM; kt += 32) {
        const bool more = (kt + 32) < DM;
        if (more) {
            __builtin_amdgcn_global_load_lds((gp1)(const void*)(Ag + kt + 32), (lp3)(void*)&As[cur ^ 1][soff], 16, 0, 0);
            __builtin_amdgcn_global_load_lds((gp1)(const void*)(Bg + kt + 32), (lp3)(void*)&Bs[cur ^ 1][soff], 16, 0, 0);
        }
        short8 af[2], bf[2];
#pragma unroll
        for (int i = 0; i < 2; ++i) af[i] = *(const short8*)&As[cur][(wh * 32 + i * 16 + l16) * 32 + quad * 8];
#pragma unroll
        for (int j = 0; j < 2; ++j) bf[j] = *(const short8*)&Bs[cur][(ww * 32 + j * 16 + l16) * 32 + quad * 8];
#pragma unroll
        for (int i = 0; i < 2; ++i)
#pragma unroll
            for (int j = 0; j < 2; ++j)
                acc[i][j] = __builtin_amdgcn_mfma_f32_16x16x32_bf16(af[i], bf[j], acc[i][j], 0, 0, 0);
        if (more) {
            __syncthreads();
            cur ^= 1;
        }
    }
    const int row0 = bx * 64 + wh * 32;
    const int col0 = by * 64 + ww * 32;
#pragma unroll
    for (int i = 0; i < 2; ++i)
#pragma unroll
        for (int j = 0; j < 2; ++j)
#pragma unroll
            for (int r = 0; r < 4; ++r)
                C[(size_t)(row0 + i * 16 + quad * 4 + r) * DM + col0 + j * 16 + l16] = acc[i][j][r];
}

extern "C" void kernel_launch(void* const* d_in, const int* in_sizes, int n_in,
                              void* d_out, int out_size, void* d_ws, size_t ws_size,
                              hipStream_t stream) {
    const float* q = (const float*)d_in[0];
    const float* k = (const float*)d_in[1];
    const float* v = (const float*)d_in[2];
    const int* mask = (const int*)d_in[3];
    const float* Wq = (const float*)d_in[4];
    const float* Wk = (const float*)d_in[5];
    const float* Wv = (const float*)d_in[6];
    const float* Wo = (const float*)d_in[7];
    float* out = (float*)d_out;

    char* ws = (char*)d_ws;
    size_t off = 0;
    auto alloc = [&](size_t bytes) {
        void* p = ws + off;
        off += (bytes + 255) & ~(size_t)255;
        return p;
    };
    const size_t MAT = (size_t)MROWS * DM * 2;      // 6291456 B
    const size_t WMAT = (size_t)DM * DM * 2;        // 1179648 B
    // Layout: WoT | qh kh vhT | pmask | lsb | [WqT WkT WvT ... pob overlays here]
    // ao overlays qh (dead after attn; merge runs after attn in-stream).
    unsigned short* WoT = (unsigned short*)alloc(WMAT);
    unsigned short* qh  = (unsigned short*)alloc(MAT);
    unsigned short* kh  = (unsigned short*)alloc(MAT);
    unsigned short* vhT = (unsigned short*)alloc(MAT);
    uint32_t* pmask     = (uint32_t*)alloc((size_t)NB * S_LEN * 64 * 4);
    float* lsb          = (float*)alloc((size_t)8 * NH * S_LEN * 4);
    unsigned short* WqT = (unsigned short*)alloc(WMAT);
    unsigned short* WkT = (unsigned short*)alloc(WMAT);
    unsigned short* WvT = (unsigned short*)alloc(WMAT);
    unsigned short* pob = WqT;  // overlays WqT/WkT/WvT + extends (dead after proj_gemm)
    (void)alloc((size_t)8 * S_LEN * DM * 2 - 3 * WMAT);  // reserve pob tail
    unsigned short* ao = qh;    // overlays qh (dead after attn)

    prep_kernel<<<dim3(576 + 4096), 256, 0, stream>>>(Wq, Wk, Wv, Wo, mask,
                                                      WqT, WkT, WvT, WoT, pmask);
    proj_gemm<<<dim3(1152), 256, 0, stream>>>(q, k, v, WqT, WkT, WvT, qh, kh, vhT);
    attn_kernel<<<dim3(1536), 256, 0, stream>>>(qh, kh, vhT, pmask, pob, lsb);
    merge_kernel<<<dim3(3072), 256, 0, stream>>>(pob, lsb, ao);
    out_gemm<<<dim3(768), 256, 0, stream>>>(ao, WoT, out);
}

// Round 11
// 217.383 us; speedup vs baseline: 1.0163x; 1.0163x over previous
//
#include <hip/hip_runtime.h>
#include <stdint.h>

#define S_LEN 2048
#define NH 12
#define DM 768
#define DK 64
#define NB 2
#define MROWS (NB * S_LEN)  // 4096

typedef __attribute__((ext_vector_type(8))) short short8;
typedef __attribute__((ext_vector_type(4))) float f32x4;
typedef __attribute__((ext_vector_type(4))) uint32_t u32x4;

__device__ __forceinline__ unsigned short bf16rne(float f) {
    union { float f; uint32_t u; } v; v.f = f;
    return (unsigned short)((v.u + 0x7FFFu + ((v.u >> 16) & 1u)) >> 16);
}

__device__ __forceinline__ uint32_t cvtpk(float lo, float hi) {
    uint32_t r;
    asm("v_cvt_pk_bf16_f32 %0, %1, %2" : "=v"(r) : "v"(lo), "v"(hi));
    return r;
}

// ---------------- prep: tiled LDS weight transpose + mask bit-pack ----------------
__global__ __launch_bounds__(256) void prep_kernel(
        const float* __restrict__ Wq, const float* __restrict__ Wk,
        const float* __restrict__ Wv, const float* __restrict__ Wo,
        const int* __restrict__ mask,
        unsigned short* __restrict__ WqT, unsigned short* __restrict__ WkT,
        unsigned short* __restrict__ WvT, unsigned short* __restrict__ WoT,
        uint32_t* __restrict__ pm) {
    const int bx = blockIdx.x, tid = threadIdx.x;
    if (bx < 576) {
        __shared__ __align__(16) unsigned short L[64 * 72];
        int kd0, n0;
        unsigned short* WT;
        if (bx < 432) {
            int which = bx / 144;
            int t2 = bx % 144;
            int h = t2 / 12; kd0 = (t2 % 12) * 64; n0 = h * 64;
            const float* W = (which == 0) ? Wq : (which == 1) ? Wk : Wv;
            WT = (which == 0) ? WqT : (which == 1) ? WkT : WvT;
            const int r = tid >> 2, c0 = (tid & 3) << 4;
            const size_t roff = ((size_t)(h * 768 + kd0 + r)) * 64 + c0;
            float4 f[4];
#pragma unroll
            for (int i = 0; i < 4; ++i) f[i] = *(const float4*)(W + roff + i * 4);
            const float scl = (which == 0) ? 0.18033688011112042f : 1.0f;
#pragma unroll
            for (int i = 0; i < 4; ++i) {
                L[(c0 + i * 4 + 0) * 72 + r] = bf16rne(f[i].x * scl);
                L[(c0 + i * 4 + 1) * 72 + r] = bf16rne(f[i].y * scl);
                L[(c0 + i * 4 + 2) * 72 + r] = bf16rne(f[i].z * scl);
                L[(c0 + i * 4 + 3) * 72 + r] = bf16rne(f[i].w * scl);
            }
        } else {
            int t3 = bx - 432;
            kd0 = (t3 / 12) * 64; n0 = (t3 % 12) * 64;
            WT = WoT;
            const int r = tid >> 2, c0 = (tid & 3) << 4;
            const size_t roff = ((size_t)(kd0 + r)) * 768 + n0 + c0;
            float4 f[4];
#pragma unroll
            for (int i = 0; i < 4; ++i) f[i] = *(const float4*)(Wo + roff + i * 4);
#pragma unroll
            for (int i = 0; i < 4; ++i) {
                L[(c0 + i * 4 + 0) * 72 + r] = bf16rne(f[i].x);
                L[(c0 + i * 4 + 1) * 72 + r] = bf16rne(f[i].y);
                L[(c0 + i * 4 + 2) * 72 + r] = bf16rne(f[i].z);
                L[(c0 + i * 4 + 3) * 72 + r] = bf16rne(f[i].w);
            }
        }
        __syncthreads();
        const int nl = tid >> 2, cc = (tid & 3) << 4;
        short8 v0 = *(const short8*)&L[nl * 72 + cc];
        short8 v1 = *(const short8*)&L[nl * 72 + cc + 8];
        *(short8*)&WT[(size_t)(n0 + nl) * DM + kd0 + cc] = v0;
        *(short8*)&WT[(size_t)(n0 + nl) * DM + kd0 + cc + 8] = v1;
    } else {
        int t = (bx - 576) * 256 + tid;  // 1,048,576 threads
        const int4* mp = (const int4*)mask;
        int4 a = mp[2 * t], b = mp[2 * t + 1];
        unsigned int by =
            (a.x != 0 ? 1u : 0u)  | (a.y != 0 ? 2u : 0u)  | (a.z != 0 ? 4u : 0u)  | (a.w != 0 ? 8u : 0u) |
            (b.x != 0 ? 16u : 0u) | (b.y != 0 ? 32u : 0u) | (b.z != 0 ? 64u : 0u) | (b.w != 0 ? 128u : 0u);
        ((unsigned char*)pm)[t] = (unsigned char)by;
    }
}

// ---------------- projections: 128x128 tiles, BK=64 (two proven 32-col sub-stages per barrier pair) ----------------
// Halves the __syncthreads vmcnt(0) drain count (24 steps -> 12) at zero layout risk: each half
// is the byte-identical R4/R9 staging (64B-stride rows, conflict-free). Grid 576, XCD-chunked.
__global__ __launch_bounds__(256) void proj_gemm(
        const float* __restrict__ qf32, const float* __restrict__ kf32,
        const float* __restrict__ vf32,
        const unsigned short* __restrict__ WqT, const unsigned short* __restrict__ WkT,
        const unsigned short* __restrict__ WvT,
        unsigned short* __restrict__ qh, unsigned short* __restrict__ kh,
        unsigned short* __restrict__ vhT) {
    __shared__ __align__(16) unsigned short As[2][128 * 32];   // [k-half][row][32]
    __shared__ __align__(16) unsigned short Bs[2][128 * 32];
    const int bid = blockIdx.x;
    const int xcd = bid & 7, pos = bid >> 3;     // 72 per XCD
    const int widx = xcd * 72 + pos;
    const int oi = widx / 6, by = widx % 6;
    const int z = oi >> 5, bx = oi & 31;
    const float* A = (z == 0) ? qf32 : (z == 1) ? kf32 : vf32;
    const unsigned short* BT = (z == 0) ? WqT : (z == 1) ? WkT : WvT;
    const int tid = threadIdx.x;
    const int lane = tid & 63, wid = tid >> 6;
    const int ww = wid & 1, wh = wid >> 1;
    const int quad = lane >> 4, l16 = lane & 15;
    const int lr = lane >> 2, lc = (lane & 3) * 8;
    typedef __attribute__((address_space(1))) const unsigned int* gp1;
    typedef __attribute__((address_space(3))) unsigned int* lp3;
    const float* Ag0 = A + (size_t)(bx * 128 + wid * 32 + lr) * DM + lc;
    const float* Ag1 = Ag0 + 16 * DM;
    const unsigned short* Bg = BT + (size_t)(by * 128 + wid * 32 + lr) * DM + lc;
    const int wb = wid * 1024;

    f32x4 acc[4][4] = {};
    for (int kt = 0; kt < DM; kt += 64) {
        __syncthreads();
        // issue all global ops for both k-halves up front
        __builtin_amdgcn_global_load_lds((gp1)(const void*)(Bg + kt),                (lp3)(void*)&Bs[0][wb],       16, 0, 0);
        __builtin_amdgcn_global_load_lds((gp1)(const void*)(Bg + 16 * DM + kt),      (lp3)(void*)&Bs[0][wb + 512], 16, 0, 0);
        __builtin_amdgcn_global_load_lds((gp1)(const void*)(Bg + kt + 32),           (lp3)(void*)&Bs[1][wb],       16, 0, 0);
        __builtin_amdgcn_global_load_lds((gp1)(const void*)(Bg + 16 * DM + kt + 32), (lp3)(void*)&Bs[1][wb + 512], 16, 0, 0);
        float4 x0 = *(const float4*)(Ag0 + kt),      x1 = *(const float4*)(Ag0 + kt + 4);
        float4 y0 = *(const float4*)(Ag1 + kt),      y1 = *(const float4*)(Ag1 + kt + 4);
        float4 x2 = *(const float4*)(Ag0 + kt + 32), x3 = *(const float4*)(Ag0 + kt + 36);
        float4 y2 = *(const float4*)(Ag1 + kt + 32), y3 = *(const float4*)(Ag1 + kt + 36);
        u32x4 ua, ub;
        ua[0] = cvtpk(x0.x, x0.y); ua[1] = cvtpk(x0.z, x0.w);
        ua[2] = cvtpk(x1.x, x1.y); ua[3] = cvtpk(x1.z, x1.w);
        ub[0] = cvtpk(y0.x, y0.y); ub[1] = cvtpk(y0.z, y0.w);
        ub[2] = cvtpk(y1.x, y1.y); ub[3] = cvtpk(y1.z, y1.w);
        *(u32x4*)&As[0][wb + lr * 32 + lc] = ua;
        *(u32x4*)&As[0][wb + (16 + lr) * 32 + lc] = ub;
        ua[0] = cvtpk(x2.x, x2.y); ua[1] = cvtpk(x2.z, x2.w);
        ua[2] = cvtpk(x3.x, x3.y); ua[3] = cvtpk(x3.z, x3.w);
        ub[0] = cvtpk(y2.x, y2.y); ub[1] = cvtpk(y2.z, y2.w);
        ub[2] = cvtpk(y3.x, y3.y); ub[3] = cvtpk(y3.z, y3.w);
        *(u32x4*)&As[1][wb + lr * 32 + lc] = ua;
        *(u32x4*)&As[1][wb + (16 + lr) * 32 + lc] = ub;
        __syncthreads();
        short8 af0[4], af1[4], bf0[4], bf1[4];
#pragma unroll
        for (int i = 0; i < 4; ++i) {
            af0[i] = *(const short8*)&As[0][(wh * 64 + i * 16 + l16) * 32 + quad * 8];
            af1[i] = *(const short8*)&As[1][(wh * 64 + i * 16 + l16) * 32 + quad * 8];
        }
#pragma unroll
        for (int j = 0; j < 4; ++j) {
            bf0[j] = *(const short8*)&Bs[0][(ww * 64 + j * 16 + l16) * 32 + quad * 8];
            bf1[j] = *(const short8*)&Bs[1][(ww * 64 + j * 16 + l16) * 32 + quad * 8];
        }
#pragma unroll
        for (int i = 0; i < 4; ++i)
#pragma unroll
            for (int j = 0; j < 4; ++j) {
                acc[i][j] = __builtin_amdgcn_mfma_f32_16x16x32_bf16(af0[i], bf0[j], acc[i][j], 0, 0, 0);
                acc[i][j] = __builtin_amdgcn_mfma_f32_16x16x32_bf16(af1[i], bf1[j], acc[i][j], 0, 0, 0);
            }
    }

    const int row0 = bx * 128 + wh * 64;
    const int col0 = by * 128 + ww * 64;
    if (z < 2) {
        unsigned short* C = z ? kh : qh;
#pragma unroll
        for (int i = 0; i < 4; ++i)
#pragma unroll
            for (int j = 0; j < 4; ++j)
#pragma unroll
                for (int r = 0; r < 4; ++r)
                    C[(size_t)(row0 + i * 16 + quad * 4 + r) * DM + col0 + j * 16 + l16] = bf16rne(acc[i][j][r]);
    } else {
#pragma unroll
        for (int i = 0; i < 4; ++i)
#pragma unroll
            for (int j = 0; j < 4; ++j) {
                int row = row0 + i * 16 + quad * 4;  // = b*2048 + s, 4 consecutive s
                int col = col0 + j * 16 + l16;       // = h*64 + d
                int bb = row >> 11, s = row & 2047;
                int hh = col >> 6, d = col & 63;
                // key bit-permute within 64-group (preserves low 2 bits -> uint2 write contiguous)
                int g = (s >> 2) & 15;
                int pg = (g & 8) | ((g & 3) << 1) | ((g & 4) >> 2);
                int sp = (s & ~63) | (pg << 2) | (s & 3);
                uint32_t lo = (uint32_t)bf16rne(acc[i][j][0]) | ((uint32_t)bf16rne(acc[i][j][1]) << 16);
                uint32_t hi = (uint32_t)bf16rne(acc[i][j][2]) | ((uint32_t)bf16rne(acc[i][j][3]) << 16);
                uint2 o = make_uint2(lo, hi);
                *(uint2*)&vhT[(size_t)((bb * NH + hh) * DK + d) * S_LEN + sp] = o;
            }
    }
}

// ---------------- flash attention: K-split 4, XCD-swizzled, dbuf LDS (1 barrier/tile) ----------------
__global__ __launch_bounds__(256) void attn_kernel(
        const unsigned short* __restrict__ qh, const unsigned short* __restrict__ kh,
        const unsigned short* __restrict__ vhT, const uint32_t* __restrict__ pm,
        unsigned short* __restrict__ pob, float* __restrict__ lsb) {
    const int bid = blockIdx.x;
    const int xcd = bid & 7, pos = bid >> 3;
    const int wkr = xcd * 192 + pos;
    const int qt = wkr & 15;
    const int hz = wkr >> 4;       // 0..95
    const int h = hz % 12;
    const int z = hz / 12;         // 0..7 = b*4 + ks
    const int b = z >> 2, ks = z & 3;
    const int tid = threadIdx.x, w = tid >> 6, lane = tid & 63;
    const int quad = lane >> 4, l16 = lane & 15;
    __shared__ __align__(16) unsigned short SMEM[2 * 2 * 64 * 64];  // dbuf x (Ks|Vs), 32 KiB

    const int qrow0 = qt * 128 + w * 32;
    short8 qf[2][2];
#pragma unroll
    for (int mi = 0; mi < 2; ++mi) {
        const size_t qbase = (size_t)(b * S_LEN + qrow0 + mi * 16 + l16) * DM + h * DK;
        qf[mi][0] = *(const short8*)&qh[qbase + quad * 8];
        qf[mi][1] = *(const short8*)&qh[qbase + 32 + quad * 8];
    }
    short8 of = {};
    if (l16 == 0) {
#pragma unroll
        for (int j = 0; j < 8; ++j) of[j] = (short)0x3F80;
    }

    f32x4 out_t[2][4] = {};  // [mi][c2]: C[d][q], d = c2*16 + quad*4 + r, q = l16
    f32x4 outl[2] = {};

    const int srow = tid >> 2, scol = (tid & 3) << 4;
    const int ssw = (srow & 7) << 3;
    const int sc0 = srow * 64 + (scol ^ ssw);
    const int sc1 = srow * 64 + ((scol + 8) ^ ssw);
    const unsigned short* Kg = kh + (size_t)b * S_LEN * DM + h * DK;
    const unsigned short* Vg = vhT + (size_t)((b * NH + h) * DK) * S_LEN;
    const int kt0 = ks * (S_LEN / 4);
    const int NT = (S_LEN / 4) / 64;  // 8 tiles

    {
        short8 a0 = *(const short8*)&Kg[(size_t)(kt0 + srow) * DM + scol];
        short8 a1 = *(const short8*)&Kg[(size_t)(kt0 + srow) * DM + scol + 8];
        short8 a2 = *(const short8*)&Vg[(size_t)srow * S_LEN + kt0 + scol];
        short8 a3 = *(const short8*)&Vg[(size_t)srow * S_LEN + kt0 + scol + 8];
        *(short8*)&SMEM[sc0] = a0;
        *(short8*)&SMEM[sc1] = a1;
        *(short8*)&SMEM[4096 + sc0] = a2;
        *(short8*)&SMEM[4096 + sc1] = a3;
    }
    __syncthreads();

    int cur = 0;
    for (int t = 0; t < NT; ++t) {
        const int kt = kt0 + t * 64;
        const bool more = (t + 1 < NT);
        short8 kr0, kr1, vr0, vr1;
        if (more) {
            const int kn = kt + 64;
            kr0 = *(const short8*)&Kg[(size_t)(kn + srow) * DM + scol];
            kr1 = *(const short8*)&Kg[(size_t)(kn + srow) * DM + scol + 8];
            vr0 = *(const short8*)&Vg[(size_t)srow * S_LEN + kn + scol];
            vr1 = *(const short8*)&Vg[(size_t)srow * S_LEN + kn + scol + 8];
        }
        uint2 mw[2];
#pragma unroll
        for (int mi = 0; mi < 2; ++mi)
            mw[mi] = *(const uint2*)&pm[(size_t)(b * S_LEN + qrow0 + mi * 16 + l16) * 64 + (kt >> 5)];

        const unsigned short* Ks = SMEM + cur * 8192;
        const unsigned short* Vs = Ks + 4096;

        u32x4 pf32[2][2];
#pragma unroll
        for (int cb = 0; cb < 4; ++cb) {
            const int krw = cb * 16 + l16, ksw = (krw & 7) << 3;
            short8 kf0 = *(const short8*)&Ks[krw * 64 + ((quad * 8) ^ ksw)];
            short8 kf1 = *(const short8*)&Ks[krw * 64 + ((32 + quad * 8) ^ ksw)];
#pragma unroll
            for (int mi = 0; mi < 2; ++mi) {
                f32x4 zz = {0.f, 0.f, 0.f, 0.f};
                zz = __builtin_amdgcn_mfma_f32_16x16x32_bf16(kf0, qf[mi][0], zz, 0, 0, 0);
                zz = __builtin_amdgcn_mfma_f32_16x16x32_bf16(kf1, qf[mi][1], zz, 0, 0, 0);
                uint32_t mword = (cb & 2) ? mw[mi].y : mw[mi].x;
                float e[4];
#pragma unroll
                for (int r = 0; r < 4; ++r) {
                    float ev = __builtin_amdgcn_exp2f(zz[r]);
                    int32_t mneg = __builtin_amdgcn_sbfe((int32_t)mword, ((cb & 1) << 4) + quad * 4 + r, 1);
                    e[r] = __uint_as_float(__float_as_uint(ev) & (uint32_t)mneg);
                }
                pf32[mi][cb >> 1][(cb & 1) * 2 + 0] = cvtpk(e[0], e[1]);
                pf32[mi][cb >> 1][(cb & 1) * 2 + 1] = cvtpk(e[2], e[3]);
            }
        }
        short8 pf[2][2];
#pragma unroll
        for (int mi = 0; mi < 2; ++mi) {
            pf[mi][0] = __builtin_bit_cast(short8, pf32[mi][0]);
            pf[mi][1] = __builtin_bit_cast(short8, pf32[mi][1]);
        }

        __builtin_amdgcn_s_setprio(1);
#pragma unroll
        for (int c2 = 0; c2 < 4; ++c2) {
            const int vrw = c2 * 16 + l16, vsw = (vrw & 7) << 3;
            short8 vf0 = *(const short8*)&Vs[vrw * 64 + ((quad * 8) ^ vsw)];
            short8 vf1 = *(const short8*)&Vs[vrw * 64 + ((32 + quad * 8) ^ vsw)];
#pragma unroll
            for (int mi = 0; mi < 2; ++mi) {
                out_t[mi][c2] = __builtin_amdgcn_mfma_f32_16x16x32_bf16(vf0, pf[mi][0], out_t[mi][c2], 0, 0, 0);
                out_t[mi][c2] = __builtin_amdgcn_mfma_f32_16x16x32_bf16(vf1, pf[mi][1], out_t[mi][c2], 0, 0, 0);
            }
        }
#pragma unroll
        for (int mi = 0; mi < 2; ++mi) {
            outl[mi] = __builtin_amdgcn_mfma_f32_16x16x32_bf16(of, pf[mi][0], outl[mi], 0, 0, 0);
            outl[mi] = __builtin_amdgcn_mfma_f32_16x16x32_bf16(of, pf[mi][1], outl[mi], 0, 0, 0);
        }
        __builtin_amdgcn_s_setprio(0);

        if (more) {
            unsigned short* Kn = SMEM + (cur ^ 1) * 8192;
            *(short8*)&Kn[sc0] = kr0;
            *(short8*)&Kn[sc1] = kr1;
            *(short8*)&Kn[4096 + sc0] = vr0;
            *(short8*)&Kn[4096 + sc1] = vr1;
            __syncthreads();
            cur ^= 1;
        }
    }

    const int pz = z;
    if (quad == 0) {
#pragma unroll
        for (int mi = 0; mi < 2; ++mi)
            lsb[((size_t)pz * NH + h) * S_LEN + qrow0 + mi * 16 + l16] = outl[mi][0];
    }

    __syncthreads();
    unsigned short* Os = SMEM + w * 2048;
#pragma unroll
    for (int mi = 0; mi < 2; ++mi) {
        const int orow = mi * 16 + l16, osw = (orow & 7) << 3;
#pragma unroll
        for (int c2 = 0; c2 < 4; ++c2) {
            uint2 pw2;
            pw2.x = cvtpk(out_t[mi][c2][0], out_t[mi][c2][1]);
            pw2.y = cvtpk(out_t[mi][c2][2], out_t[mi][c2][3]);
            *(uint2*)&Os[orow * 64 + ((c2 * 16 + quad * 4) ^ osw)] = pw2;
        }
    }
    const int ql = lane >> 1, hf = lane & 1;
    const int qsw = (ql & 7) << 3;
    const int qg = qrow0 + ql;
    const size_t orowg = ((size_t)pz * S_LEN + qg) * DM + h * DK + hf * 32;
#pragma unroll
    for (int k2 = 0; k2 < 4; ++k2)
        *(short8*)&pob[orowg + k2 * 8] = *(const short8*)&Os[ql * 64 + ((hf * 32 + k2 * 8) ^ qsw)];
}

// ---------------- merge the four K-chunk partials -> ao bf16 ----------------
__global__ __launch_bounds__(256) void merge_kernel(const unsigned short* __restrict__ pob,
                                                    const float* __restrict__ lsb,
                                                    unsigned short* __restrict__ ao) {
    int t = blockIdx.x * 256 + threadIdx.x;   // 786432 threads, 4 elems each
    int sg = t / 192;                          // b*S + s
    int c = (t - sg * 192) * 4;                // col in [0,768)
    int b = sg >> 11, s = sg & 2047, h = c >> 6;
    float l = 0.f;
#pragma unroll
    for (int ksp = 0; ksp < 4; ++ksp)
        l += lsb[((size_t)(b * 4 + ksp) * NH + h) * S_LEN + s];
    float rl = 1.f / fmaxf(l, 1e-37f);
    float f0 = 0.f, f1 = 0.f, f2 = 0.f, f3 = 0.f;
#pragma unroll
    for (int ksp = 0; ksp < 4; ++ksp) {
        uint2 a = *(const uint2*)&pob[((size_t)((b * 4 + ksp) * S_LEN) + s) * DM + c];
        f0 += __uint_as_float(a.x << 16);
        f1 += __uint_as_float(a.x & 0xFFFF0000u);
        f2 += __uint_as_float(a.y << 16);
        f3 += __uint_as_float(a.y & 0xFFFF0000u);
    }
    uint32_t lo = cvtpk(f0 * rl, f1 * rl);
    uint32_t hi = cvtpk(f2 * rl, f3 * rl);
    *(uint2*)&ao[(size_t)sg * DM + c] = make_uint2(lo, hi);
}

// ---------------- output projection: 64x64 tiles, BK=64 (two sub-chunks/step), dbuf 1-barrier ----------------
__global__ __launch_bounds__(256) void out_gemm(
        const unsigned short* __restrict__ ao, const unsigned short* __restrict__ WoT,
        float* __restrict__ C) {
    __shared__ __align__(16) unsigned short As[2][2][64 * 32];  // [buf][k-half]
    __shared__ __align__(16) unsigned short Bs[2][2][64 * 32];
    const int bid = blockIdx.x;
    const int xcd = bid & 7, pos = bid >> 3;   // 96 per XCD
    const int widx = xcd * 96 + pos;
    const int bx = widx / 12, by = widx % 12;  // bx 0..63, by 0..11
    const int tid = threadIdx.x;
    const int lane = tid & 63, wid = tid >> 6;
    const int ww = wid & 1, wh = wid >> 1;
    const int quad = lane >> 4, l16 = lane & 15;
    const int lr = lane >> 2, lc = (lane & 3) * 8;
    typedef __attribute__((address_space(1))) const unsigned int* gp1;
    typedef __attribute__((address_space(3))) unsigned int* lp3;
    const unsigned short* Ag = ao  + (size_t)(bx * 64 + wid * 16 + lr) * DM + lc;
    const unsigned short* Bg = WoT + (size_t)(by * 64 + wid * 16 + lr) * DM + lc;
    const int soff = wid * 512;
    f32x4 acc[2][2] = {};
    __builtin_amdgcn_global_load_lds((gp1)(const void*)Ag,        (lp3)(void*)&As[0][0][soff], 16, 0, 0);
    __builtin_amdgcn_global_load_lds((gp1)(const void*)(Ag + 32), (lp3)(void*)&As[0][1][soff], 16, 0, 0);
    __builtin_amdgcn_global_load_lds((gp1)(const void*)Bg,        (lp3)(void*)&Bs[0][0][soff], 16, 0, 0);
    __builtin_amdgcn_global_load_lds((gp1)(const void*)(Bg + 32), (lp3)(void*)&Bs[0][1][soff], 16, 0, 0);
    __syncthreads();
    int cur = 0;
    for (int kt = 0; kt < DM; kt += 64) {
        const bool more = (kt + 64) < DM;
        if (more) {
            __builtin_amdgcn_global_load_lds((gp1)(const void*)(Ag + kt + 64), (lp3)(void*)&As[cur ^ 1][0][soff], 16, 0, 0);
            __builtin_amdgcn_global_load_lds((gp1)(const void*)(Ag + kt + 96), (lp3)(void*)&As[cur ^ 1][1][soff], 16, 0, 0);
            __builtin_amdgcn_global_load_lds((gp1)(const void*)(Bg + kt + 64), (lp3)(void*)&Bs[cur ^ 1][0][soff], 16, 0, 0);
            __builtin_amdgcn_global_load_lds((gp1)(const void*)(Bg + kt + 96), (lp3)(void*)&Bs[cur ^ 1][1][soff], 16, 0, 0);
        }
        short8 af0[2], af1[2], bf0[2], bf1[2];
#pragma unroll
        for (int i = 0; i < 2; ++i) {
            af0[i] = *(const short8*)&As[cur][0][(wh * 32 + i * 16 + l16) * 32 + quad * 8];
            af1[i] = *(const short8*)&As[cur][1][(wh * 32 + i * 16 + l16) * 32 + quad * 8];
        }
#pragma unroll
        for (int j = 0; j < 2; ++j) {
            bf0[j] = *(const short8*)&Bs[cur][0][(ww * 32 + j * 16 + l16) * 32 + quad * 8];
            bf1[j] = *(const short8*)&Bs[cur][1][(ww * 32 + j * 16 + l16) * 32 + quad * 8];
        }
#pragma unroll
        for (int i = 0; i < 2; ++i)
#pragma unroll
            for (int j = 0; j < 2; ++j) {
                acc[i][j] = __builtin_amdgcn_mfma_f32_16x16x32_bf16(af0[i], bf0[j], acc[i][j], 0, 0, 0);
                acc[i][j] = __builtin_amdgcn_mfma_f32_16x16x32_bf16(af1[i], bf1[j], acc[i][j], 0, 0, 0);
            }
        if (more) {
            __syncthreads();
            cur ^= 1;
        }
    }
    const int row0 = bx * 64 + wh * 32;
    const int col0 = by * 64 + ww * 32;
#pragma unroll
    for (int i = 0; i < 2; ++i)
#pragma unroll
        for (int j = 0; j < 2; ++j)
#pragma unroll
            for (int r = 0; r < 4; ++r)
                C[(size_t)(row0 + i * 16 + quad * 4 + r) * DM + col0 + j * 16 + l16] = acc[i][j][r];
}

extern "C" void kernel_launch(void* const* d_in, const int* in_sizes, int n_in,
                              void* d_out, int out_size, void* d_ws, size_t ws_size,
                              hipStream_t stream) {
    const float* q = (const float*)d_in[0];
    const float* k = (const float*)d_in[1];
    const float* v = (const float*)d_in[2];
    const int* mask = (const int*)d_in[3];
    const float* Wq = (const float*)d_in[4];
    const float* Wk = (const float*)d_in[5];
    const float* Wv = (const float*)d_in[6];
    const float* Wo = (const float*)d_in[7];
    float* out = (float*)d_out;

    char* ws = (char*)d_ws;
    size_t off = 0;
    auto alloc = [&](size_t bytes) {
        void* p = ws + off;
        off += (bytes + 255) & ~(size_t)255;
        return p;
    };
    const size_t MAT = (size_t)MROWS * DM * 2;      // 6291456 B
    const size_t WMAT = (size_t)DM * DM * 2;        // 1179648 B
    // Layout: WoT | qh kh vhT | pmask | lsb | [WqT WkT WvT ... pob overlays here]
    // ao overlays qh (dead after attn; merge runs after attn in-stream).
    unsigned short* WoT = (unsigned short*)alloc(WMAT);
    unsigned short* qh  = (unsigned short*)alloc(MAT);
    unsigned short* kh  = (unsigned short*)alloc(MAT);
    unsigned short* vhT = (unsigned short*)alloc(MAT);
    uint32_t* pmask     = (uint32_t*)alloc((size_t)NB * S_LEN * 64 * 4);
    float* lsb          = (float*)alloc((size_t)8 * NH * S_LEN * 4);
    unsigned short* WqT = (unsigned short*)alloc(WMAT);
    unsigned short* WkT = (unsigned short*)alloc(WMAT);
    unsigned short* WvT = (unsigned short*)alloc(WMAT);
    unsigned short* pob = WqT;  // overlays WqT/WkT/WvT + extends (dead after proj_gemm)
    (void)alloc((size_t)8 * S_LEN * DM * 2 - 3 * WMAT);  // reserve pob tail
    unsigned short* ao = qh;    // overlays qh (dead after attn)

    prep_kernel<<<dim3(576 + 4096), 256, 0, stream>>>(Wq, Wk, Wv, Wo, mask,
                                                      WqT, WkT, WvT, WoT, pmask);
    proj_gemm<<<dim3(576), 256, 0, stream>>>(q, k, v, WqT, WkT, WvT, qh, kh, vhT);
    attn_kernel<<<dim3(1536), 256, 0, stream>>>(qh, kh, vhT, pmask, pob, lsb);
    merge_kernel<<<dim3(3072), 256, 0, stream>>>(pob, lsb, ao);
    out_gemm<<<dim3(768), 256, 0, stream>>>(ao, WoT, out);
}

// Round 12
// 211.546 us; speedup vs baseline: 1.0443x; 1.0276x over previous
//
#include <hip/hip_runtime.h>
#include <stdint.h>

#define S_LEN 2048
#define NH 12
#define DM 768
#define DK 64
#define NB 2
#define MROWS (NB * S_LEN)  // 4096

typedef __attribute__((ext_vector_type(8))) short short8;
typedef __attribute__((ext_vector_type(4))) float f32x4;
typedef __attribute__((ext_vector_type(4))) uint32_t u32x4;

__device__ __forceinline__ unsigned short bf16rne(float f) {
    union { float f; uint32_t u; } v; v.f = f;
    return (unsigned short)((v.u + 0x7FFFu + ((v.u >> 16) & 1u)) >> 16);
}

__device__ __forceinline__ uint32_t cvtpk(float lo, float hi) {
    uint32_t r;
    asm("v_cvt_pk_bf16_f32 %0, %1, %2" : "=v"(r) : "v"(lo), "v"(hi));
    return r;
}

// ---------------- prep: tiled LDS weight transpose + mask bit-pack ----------------
__global__ __launch_bounds__(256) void prep_kernel(
        const float* __restrict__ Wq, const float* __restrict__ Wk,
        const float* __restrict__ Wv, const float* __restrict__ Wo,
        const int* __restrict__ mask,
        unsigned short* __restrict__ WqT, unsigned short* __restrict__ WkT,
        unsigned short* __restrict__ WvT, unsigned short* __restrict__ WoT,
        uint32_t* __restrict__ pm) {
    const int bx = blockIdx.x, tid = threadIdx.x;
    if (bx < 576) {
        __shared__ __align__(16) unsigned short L[64 * 72];
        int kd0, n0;
        unsigned short* WT;
        if (bx < 432) {
            int which = bx / 144;
            int t2 = bx % 144;
            int h = t2 / 12; kd0 = (t2 % 12) * 64; n0 = h * 64;
            const float* W = (which == 0) ? Wq : (which == 1) ? Wk : Wv;
            WT = (which == 0) ? WqT : (which == 1) ? WkT : WvT;
            const int r = tid >> 2, c0 = (tid & 3) << 4;
            const size_t roff = ((size_t)(h * 768 + kd0 + r)) * 64 + c0;
            float4 f[4];
#pragma unroll
            for (int i = 0; i < 4; ++i) f[i] = *(const float4*)(W + roff + i * 4);
            const float scl = (which == 0) ? 0.18033688011112042f : 1.0f;
#pragma unroll
            for (int i = 0; i < 4; ++i) {
                L[(c0 + i * 4 + 0) * 72 + r] = bf16rne(f[i].x * scl);
                L[(c0 + i * 4 + 1) * 72 + r] = bf16rne(f[i].y * scl);
                L[(c0 + i * 4 + 2) * 72 + r] = bf16rne(f[i].z * scl);
                L[(c0 + i * 4 + 3) * 72 + r] = bf16rne(f[i].w * scl);
            }
        } else {
            int t3 = bx - 432;
            kd0 = (t3 / 12) * 64; n0 = (t3 % 12) * 64;
            WT = WoT;
            const int r = tid >> 2, c0 = (tid & 3) << 4;
            const size_t roff = ((size_t)(kd0 + r)) * 768 + n0 + c0;
            float4 f[4];
#pragma unroll
            for (int i = 0; i < 4; ++i) f[i] = *(const float4*)(Wo + roff + i * 4);
#pragma unroll
            for (int i = 0; i < 4; ++i) {
                L[(c0 + i * 4 + 0) * 72 + r] = bf16rne(f[i].x);
                L[(c0 + i * 4 + 1) * 72 + r] = bf16rne(f[i].y);
                L[(c0 + i * 4 + 2) * 72 + r] = bf16rne(f[i].z);
                L[(c0 + i * 4 + 3) * 72 + r] = bf16rne(f[i].w);
            }
        }
        __syncthreads();
        const int nl = tid >> 2, cc = (tid & 3) << 4;
        short8 v0 = *(const short8*)&L[nl * 72 + cc];
        short8 v1 = *(const short8*)&L[nl * 72 + cc + 8];
        *(short8*)&WT[(size_t)(n0 + nl) * DM + kd0 + cc] = v0;
        *(short8*)&WT[(size_t)(n0 + nl) * DM + kd0 + cc + 8] = v1;
    } else {
        int t = (bx - 576) * 256 + tid;  // 1,048,576 threads
        const int4* mp = (const int4*)mask;
        int4 a = mp[2 * t], b = mp[2 * t + 1];
        unsigned int by =
            (a.x != 0 ? 1u : 0u)  | (a.y != 0 ? 2u : 0u)  | (a.z != 0 ? 4u : 0u)  | (a.w != 0 ? 8u : 0u) |
            (b.x != 0 ? 16u : 0u) | (b.y != 0 ? 32u : 0u) | (b.z != 0 ? 64u : 0u) | (b.w != 0 ? 128u : 0u);
        ((unsigned char*)pm)[t] = (unsigned char)by;
    }
}

// ---------------- GEMM core, f32 A input: reg-stage + cvt_pk + ds_write_b128 (measured 47.0us config) ----------------
__device__ __forceinline__ void gemm_core_f32A(const float* __restrict__ A,
                                               const unsigned short* __restrict__ BT,
                                               unsigned short* As, unsigned short* Bs,
                                               f32x4 (&acc)[4][4]) {
    const int tid = threadIdx.x;
    const int lane = tid & 63, wid = tid >> 6;
    const int ww = wid & 1, wh = wid >> 1;
    const int quad = lane >> 4, l16 = lane & 15;
    const int lr = lane >> 2;
    const int lc = (lane & 3) * 8;
    typedef __attribute__((address_space(1))) const unsigned int* gp1;
    typedef __attribute__((address_space(3))) unsigned int* lp3;
    const float* Ag0 = A + (size_t)(wid * 32 + lr) * DM + lc;
    const float* Ag1 = A + (size_t)(wid * 32 + 16 + lr) * DM + lc;
    const unsigned short* Bg = BT + (size_t)(wid * 32 + lr) * DM + lc;
    unsigned short* Al = &As[wid * 32 * 32];
    unsigned short* Bl = &Bs[wid * 32 * 32];
    for (int kt = 0; kt < DM; kt += 32) {
        __syncthreads();
        __builtin_amdgcn_global_load_lds((gp1)(const void*)(Bg + kt),            (lp3)(void*)Bl,             16, 0, 0);
        __builtin_amdgcn_global_load_lds((gp1)(const void*)(Bg + 16 * DM + kt),  (lp3)(void*)(Bl + 16 * 32), 16, 0, 0);
        float4 x0 = *(const float4*)(Ag0 + kt), x1 = *(const float4*)(Ag0 + kt + 4);
        float4 y0 = *(const float4*)(Ag1 + kt), y1 = *(const float4*)(Ag1 + kt + 4);
        u32x4 ua, ub;
        ua[0] = cvtpk(x0.x, x0.y); ua[1] = cvtpk(x0.z, x0.w);
        ua[2] = cvtpk(x1.x, x1.y); ua[3] = cvtpk(x1.z, x1.w);
        ub[0] = cvtpk(y0.x, y0.y); ub[1] = cvtpk(y0.z, y0.w);
        ub[2] = cvtpk(y1.x, y1.y); ub[3] = cvtpk(y1.z, y1.w);
        *(u32x4*)&Al[lr * 32 + lc] = ua;
        *(u32x4*)&Al[(16 + lr) * 32 + lc] = ub;
        __syncthreads();
        short8 af[4], bf[4];
#pragma unroll
        for (int i = 0; i < 4; ++i) af[i] = *(const short8*)&As[(wh * 64 + i * 16 + l16) * 32 + quad * 8];
#pragma unroll
        for (int j = 0; j < 4; ++j) bf[j] = *(const short8*)&Bs[(ww * 64 + j * 16 + l16) * 32 + quad * 8];
#pragma unroll
        for (int i = 0; i < 4; ++i)
#pragma unroll
            for (int j = 0; j < 4; ++j)
                acc[i][j] = __builtin_amdgcn_mfma_f32_16x16x32_bf16(af[i], bf[j], acc[i][j], 0, 0, 0);
    }
}

// ---------------- projections (XCD-chunked, measured-best): q,k -> [M, H*64] ; v -> vhT (key-permuted) ----------------
__global__ __launch_bounds__(256) void proj_gemm(
        const float* __restrict__ qf32, const float* __restrict__ kf32,
        const float* __restrict__ vf32,
        const unsigned short* __restrict__ WqT, const unsigned short* __restrict__ WkT,
        const unsigned short* __restrict__ WvT,
        unsigned short* __restrict__ qh, unsigned short* __restrict__ kh,
        unsigned short* __restrict__ vhT) {
    __shared__ __align__(16) unsigned short As[128 * 32];
    __shared__ __align__(16) unsigned short Bs[128 * 32];
    const int bid = blockIdx.x;
    const int xcd = bid & 7, pos = bid >> 3;     // 72 per XCD
    const int widx = xcd * 72 + pos;
    const int oi = widx / 6, by = widx % 6;
    const int z = oi >> 5, bx = oi & 31;
    const float* A = (z == 0) ? qf32 : (z == 1) ? kf32 : vf32;
    const unsigned short* BT = (z == 0) ? WqT : (z == 1) ? WkT : WvT;
    f32x4 acc[4][4] = {};
    gemm_core_f32A(A + (size_t)bx * 128 * DM, BT + (size_t)by * 128 * DM, As, Bs, acc);

    const int tid = threadIdx.x;
    const int lane = tid & 63, wid = tid >> 6;
    const int ww = wid & 1, wh = wid >> 1;
    const int quad = lane >> 4, l16 = lane & 15;
    const int row0 = bx * 128 + wh * 64;
    const int col0 = by * 128 + ww * 64;
    if (z < 2) {
        unsigned short* C = z ? kh : qh;
#pragma unroll
        for (int i = 0; i < 4; ++i)
#pragma unroll
            for (int j = 0; j < 4; ++j)
#pragma unroll
                for (int r = 0; r < 4; ++r)
                    C[(size_t)(row0 + i * 16 + quad * 4 + r) * DM + col0 + j * 16 + l16] = bf16rne(acc[i][j][r]);
    } else {
#pragma unroll
        for (int i = 0; i < 4; ++i)
#pragma unroll
            for (int j = 0; j < 4; ++j) {
                int row = row0 + i * 16 + quad * 4;  // = b*2048 + s, 4 consecutive s
                int col = col0 + j * 16 + l16;       // = h*64 + d
                int bb = row >> 11, s = row & 2047;
                int hh = col >> 6, d = col & 63;
                // key bit-permute within 64-group (preserves low 2 bits -> uint2 write contiguous)
                int g = (s >> 2) & 15;
                int pg = (g & 8) | ((g & 3) << 1) | ((g & 4) >> 2);
                int sp = (s & ~63) | (pg << 2) | (s & 3);
                uint32_t lo = (uint32_t)bf16rne(acc[i][j][0]) | ((uint32_t)bf16rne(acc[i][j][1]) << 16);
                uint32_t hi = (uint32_t)bf16rne(acc[i][j][2]) | ((uint32_t)bf16rne(acc[i][j][3]) << 16);
                uint2 o = make_uint2(lo, hi);
                *(uint2*)&vhT[(size_t)((bb * NH + hh) * DK + d) * S_LEN + sp] = o;
            }
    }
}

// ---------------- flash attention: K-split 4, XCD-swizzled, dbuf LDS (1 barrier/tile) ----------------
__global__ __launch_bounds__(256) void attn_kernel(
        const unsigned short* __restrict__ qh, const unsigned short* __restrict__ kh,
        const unsigned short* __restrict__ vhT, const uint32_t* __restrict__ pm,
        unsigned short* __restrict__ pob, float* __restrict__ lsb) {
    const int bid = blockIdx.x;
    const int xcd = bid & 7, pos = bid >> 3;
    const int wkr = xcd * 192 + pos;
    const int qt = wkr & 15;
    const int hz = wkr >> 4;       // 0..95
    const int h = hz % 12;
    const int z = hz / 12;         // 0..7 = b*4 + ks
    const int b = z >> 2, ks = z & 3;
    const int tid = threadIdx.x, w = tid >> 6, lane = tid & 63;
    const int quad = lane >> 4, l16 = lane & 15;
    __shared__ __align__(16) unsigned short SMEM[2 * 2 * 64 * 64];  // dbuf x (Ks|Vs), 32 KiB

    const int qrow0 = qt * 128 + w * 32;
    short8 qf[2][2];
#pragma unroll
    for (int mi = 0; mi < 2; ++mi) {
        const size_t qbase = (size_t)(b * S_LEN + qrow0 + mi * 16 + l16) * DM + h * DK;
        qf[mi][0] = *(const short8*)&qh[qbase + quad * 8];
        qf[mi][1] = *(const short8*)&qh[qbase + 32 + quad * 8];
    }
    short8 of = {};
    if (l16 == 0) {
#pragma unroll
        for (int j = 0; j < 8; ++j) of[j] = (short)0x3F80;
    }

    f32x4 out_t[2][4] = {};  // [mi][c2]: C[d][q], d = c2*16 + quad*4 + r, q = l16
    f32x4 outl[2] = {};

    const int srow = tid >> 2, scol = (tid & 3) << 4;
    const int ssw = (srow & 7) << 3;
    const int sc0 = srow * 64 + (scol ^ ssw);
    const int sc1 = srow * 64 + ((scol + 8) ^ ssw);
    const unsigned short* Kg = kh + (size_t)b * S_LEN * DM + h * DK;
    const unsigned short* Vg = vhT + (size_t)((b * NH + h) * DK) * S_LEN;
    const int kt0 = ks * (S_LEN / 4);
    const int NT = (S_LEN / 4) / 64;  // 8 tiles

    {
        short8 a0 = *(const short8*)&Kg[(size_t)(kt0 + srow) * DM + scol];
        short8 a1 = *(const short8*)&Kg[(size_t)(kt0 + srow) * DM + scol + 8];
        short8 a2 = *(const short8*)&Vg[(size_t)srow * S_LEN + kt0 + scol];
        short8 a3 = *(const short8*)&Vg[(size_t)srow * S_LEN + kt0 + scol + 8];
        *(short8*)&SMEM[sc0] = a0;
        *(short8*)&SMEM[sc1] = a1;
        *(short8*)&SMEM[4096 + sc0] = a2;
        *(short8*)&SMEM[4096 + sc1] = a3;
    }
    __syncthreads();

    int cur = 0;
    for (int t = 0; t < NT; ++t) {
        const int kt = kt0 + t * 64;
        const bool more = (t + 1 < NT);
        short8 kr0, kr1, vr0, vr1;
        if (more) {
            const int kn = kt + 64;
            kr0 = *(const short8*)&Kg[(size_t)(kn + srow) * DM + scol];
            kr1 = *(const short8*)&Kg[(size_t)(kn + srow) * DM + scol + 8];
            vr0 = *(const short8*)&Vg[(size_t)srow * S_LEN + kn + scol];
            vr1 = *(const short8*)&Vg[(size_t)srow * S_LEN + kn + scol + 8];
        }
        uint2 mw[2];
#pragma unroll
        for (int mi = 0; mi < 2; ++mi)
            mw[mi] = *(const uint2*)&pm[(size_t)(b * S_LEN + qrow0 + mi * 16 + l16) * 64 + (kt >> 5)];

        const unsigned short* Ks = SMEM + cur * 8192;
        const unsigned short* Vs = Ks + 4096;

        u32x4 pf32[2][2];
#pragma unroll
        for (int cb = 0; cb < 4; ++cb) {
            const int krw = cb * 16 + l16, ksw = (krw & 7) << 3;
            short8 kf0 = *(const short8*)&Ks[krw * 64 + ((quad * 8) ^ ksw)];
            short8 kf1 = *(const short8*)&Ks[krw * 64 + ((32 + quad * 8) ^ ksw)];
#pragma unroll
            for (int mi = 0; mi < 2; ++mi) {
                f32x4 zz = {0.f, 0.f, 0.f, 0.f};
                zz = __builtin_amdgcn_mfma_f32_16x16x32_bf16(kf0, qf[mi][0], zz, 0, 0, 0);
                zz = __builtin_amdgcn_mfma_f32_16x16x32_bf16(kf1, qf[mi][1], zz, 0, 0, 0);
                uint32_t mword = (cb & 2) ? mw[mi].y : mw[mi].x;
                float e[4];
#pragma unroll
                for (int r = 0; r < 4; ++r) {
                    float ev = __builtin_amdgcn_exp2f(zz[r]);
                    int32_t mneg = __builtin_amdgcn_sbfe((int32_t)mword, ((cb & 1) << 4) + quad * 4 + r, 1);
                    e[r] = __uint_as_float(__float_as_uint(ev) & (uint32_t)mneg);
                }
                pf32[mi][cb >> 1][(cb & 1) * 2 + 0] = cvtpk(e[0], e[1]);
                pf32[mi][cb >> 1][(cb & 1) * 2 + 1] = cvtpk(e[2], e[3]);
            }
        }
        short8 pf[2][2];
#pragma unroll
        for (int mi = 0; mi < 2; ++mi) {
            pf[mi][0] = __builtin_bit_cast(short8, pf32[mi][0]);
            pf[mi][1] = __builtin_bit_cast(short8, pf32[mi][1]);
        }

        __builtin_amdgcn_s_setprio(1);
#pragma unroll
        for (int c2 = 0; c2 < 4; ++c2) {
            const int vrw = c2 * 16 + l16, vsw = (vrw & 7) << 3;
            short8 vf0 = *(const short8*)&Vs[vrw * 64 + ((quad * 8) ^ vsw)];
            short8 vf1 = *(const short8*)&Vs[vrw * 64 + ((32 + quad * 8) ^ vsw)];
#pragma unroll
            for (int mi = 0; mi < 2; ++mi) {
                out_t[mi][c2] = __builtin_amdgcn_mfma_f32_16x16x32_bf16(vf0, pf[mi][0], out_t[mi][c2], 0, 0, 0);
                out_t[mi][c2] = __builtin_amdgcn_mfma_f32_16x16x32_bf16(vf1, pf[mi][1], out_t[mi][c2], 0, 0, 0);
            }
        }
#pragma unroll
        for (int mi = 0; mi < 2; ++mi) {
            outl[mi] = __builtin_amdgcn_mfma_f32_16x16x32_bf16(of, pf[mi][0], outl[mi], 0, 0, 0);
            outl[mi] = __builtin_amdgcn_mfma_f32_16x16x32_bf16(of, pf[mi][1], outl[mi], 0, 0, 0);
        }
        __builtin_amdgcn_s_setprio(0);

        if (more) {
            unsigned short* Kn = SMEM + (cur ^ 1) * 8192;
            *(short8*)&Kn[sc0] = kr0;
            *(short8*)&Kn[sc1] = kr1;
            *(short8*)&Kn[4096 + sc0] = vr0;
            *(short8*)&Kn[4096 + sc1] = vr1;
            __syncthreads();
            cur ^= 1;
        }
    }

    const int pz = z;
    if (quad == 0) {
#pragma unroll
        for (int mi = 0; mi < 2; ++mi)
            lsb[((size_t)pz * NH + h) * S_LEN + qrow0 + mi * 16 + l16] = outl[mi][0];
    }

    __syncthreads();
    unsigned short* Os = SMEM + w * 2048;
#pragma unroll
    for (int mi = 0; mi < 2; ++mi) {
        const int orow = mi * 16 + l16, osw = (orow & 7) << 3;
#pragma unroll
        for (int c2 = 0; c2 < 4; ++c2) {
            uint2 pw2;
            pw2.x = cvtpk(out_t[mi][c2][0], out_t[mi][c2][1]);
            pw2.y = cvtpk(out_t[mi][c2][2], out_t[mi][c2][3]);
            *(uint2*)&Os[orow * 64 + ((c2 * 16 + quad * 4) ^ osw)] = pw2;
        }
    }
    const int ql = lane >> 1, hf = lane & 1;
    const int qsw = (ql & 7) << 3;
    const int qg = qrow0 + ql;
    const size_t orowg = ((size_t)pz * S_LEN + qg) * DM + h * DK + hf * 32;
#pragma unroll
    for (int k2 = 0; k2 < 4; ++k2)
        *(short8*)&pob[orowg + k2 * 8] = *(const short8*)&Os[ql * 64 + ((hf * 32 + k2 * 8) ^ qsw)];
}

// ---------------- merge the four K-chunk partials -> ao bf16 ----------------
__global__ __launch_bounds__(256) void merge_kernel(const unsigned short* __restrict__ pob,
                                                    const float* __restrict__ lsb,
                                                    unsigned short* __restrict__ ao) {
    int t = blockIdx.x * 256 + threadIdx.x;   // 786432 threads, 4 elems each
    int sg = t / 192;                          // b*S + s
    int c = (t - sg * 192) * 4;                // col in [0,768)
    int b = sg >> 11, s = sg & 2047, h = c >> 6;
    float l = 0.f;
#pragma unroll
    for (int ksp = 0; ksp < 4; ++ksp)
        l += lsb[((size_t)(b * 4 + ksp) * NH + h) * S_LEN + s];
    float rl = 1.f / fmaxf(l, 1e-37f);
    float f0 = 0.f, f1 = 0.f, f2 = 0.f, f3 = 0.f;
#pragma unroll
    for (int ksp = 0; ksp < 4; ++ksp) {
        uint2 a = *(const uint2*)&pob[((size_t)((b * 4 + ksp) * S_LEN) + s) * DM + c];
        f0 += __uint_as_float(a.x << 16);
        f1 += __uint_as_float(a.x & 0xFFFF0000u);
        f2 += __uint_as_float(a.y << 16);
        f3 += __uint_as_float(a.y & 0xFFFF0000u);
    }
    uint32_t lo = cvtpk(f0 * rl, f1 * rl);
    uint32_t hi = cvtpk(f2 * rl, f3 * rl);
    *(uint2*)&ao[(size_t)sg * DM + c] = make_uint2(lo, hi);
}

// ---------------- output projection: 64x64 tiles, BK=64 (two sub-chunks/step), dbuf 1-barrier ----------------
__global__ __launch_bounds__(256) void out_gemm(
        const unsigned short* __restrict__ ao, const unsigned short* __restrict__ WoT,
        float* __restrict__ C) {
    __shared__ __align__(16) unsigned short As[2][2][64 * 32];  // [buf][k-half]
    __shared__ __align__(16) unsigned short Bs[2][2][64 * 32];
    const int bid = blockIdx.x;
    const int xcd = bid & 7, pos = bid >> 3;   // 96 per XCD
    const int widx = xcd * 96 + pos;
    const int bx = widx / 12, by = widx % 12;  // bx 0..63, by 0..11
    const int tid = threadIdx.x;
    const int lane = tid & 63, wid = tid >> 6;
    const int ww = wid & 1, wh = wid >> 1;
    const int quad = lane >> 4, l16 = lane & 15;
    const int lr = lane >> 2, lc = (lane & 3) * 8;
    typedef __attribute__((address_space(1))) const unsigned int* gp1;
    typedef __attribute__((address_space(3))) unsigned int* lp3;
    const unsigned short* Ag = ao  + (size_t)(bx * 64 + wid * 16 + lr) * DM + lc;
    const unsigned short* Bg = WoT + (size_t)(by * 64 + wid * 16 + lr) * DM + lc;
    const int soff = wid * 512;
    f32x4 acc[2][2] = {};
    __builtin_amdgcn_global_load_lds((gp1)(const void*)Ag,        (lp3)(void*)&As[0][0][soff], 16, 0, 0);
    __builtin_amdgcn_global_load_lds((gp1)(const void*)(Ag + 32), (lp3)(void*)&As[0][1][soff], 16, 0, 0);
    __builtin_amdgcn_global_load_lds((gp1)(const void*)Bg,        (lp3)(void*)&Bs[0][0][soff], 16, 0, 0);
    __builtin_amdgcn_global_load_lds((gp1)(const void*)(Bg + 32), (lp3)(void*)&Bs[0][1][soff], 16, 0, 0);
    __syncthreads();
    int cur = 0;
    for (int kt = 0; kt < DM; kt += 64) {
        const bool more = (kt + 64) < DM;
        if (more) {
            __builtin_amdgcn_global_load_lds((gp1)(const void*)(Ag + kt + 64), (lp3)(void*)&As[cur ^ 1][0][soff], 16, 0, 0);
            __builtin_amdgcn_global_load_lds((gp1)(const void*)(Ag + kt + 96), (lp3)(void*)&As[cur ^ 1][1][soff], 16, 0, 0);
            __builtin_amdgcn_global_load_lds((gp1)(const void*)(Bg + kt + 64), (lp3)(void*)&Bs[cur ^ 1][0][soff], 16, 0, 0);
            __builtin_amdgcn_global_load_lds((gp1)(const void*)(Bg + kt + 96), (lp3)(void*)&Bs[cur ^ 1][1][soff], 16, 0, 0);
        }
        short8 af0[2], af1[2], bf0[2], bf1[2];
#pragma unroll
        for (int i = 0; i < 2; ++i) {
            af0[i] = *(const short8*)&As[cur][0][(wh * 32 + i * 16 + l16) * 32 + quad * 8];
            af1[i] = *(const short8*)&As[cur][1][(wh * 32 + i * 16 + l16) * 32 + quad * 8];
        }
#pragma unroll
        for (int j = 0; j < 2; ++j) {
            bf0[j] = *(const short8*)&Bs[cur][0][(ww * 32 + j * 16 + l16) * 32 + quad * 8];
            bf1[j] = *(const short8*)&Bs[cur][1][(ww * 32 + j * 16 + l16) * 32 + quad * 8];
        }
#pragma unroll
        for (int i = 0; i < 2; ++i)
#pragma unroll
            for (int j = 0; j < 2; ++j) {
                acc[i][j] = __builtin_amdgcn_mfma_f32_16x16x32_bf16(af0[i], bf0[j], acc[i][j], 0, 0, 0);
                acc[i][j] = __builtin_amdgcn_mfma_f32_16x16x32_bf16(af1[i], bf1[j], acc[i][j], 0, 0, 0);
            }
        if (more) {
            __syncthreads();
            cur ^= 1;
        }
    }
    const int row0 = bx * 64 + wh * 32;
    const int col0 = by * 64 + ww * 32;
#pragma unroll
    for (int i = 0; i < 2; ++i)
#pragma unroll
        for (int j = 0; j < 2; ++j)
#pragma unroll
            for (int r = 0; r < 4; ++r)
                C[(size_t)(row0 + i * 16 + quad * 4 + r) * DM + col0 + j * 16 + l16] = acc[i][j][r];
}

extern "C" void kernel_launch(void* const* d_in, const int* in_sizes, int n_in,
                              void* d_out, int out_size, void* d_ws, size_t ws_size,
                              hipStream_t stream) {
    const float* q = (const float*)d_in[0];
    const float* k = (const float*)d_in[1];
    const float* v = (const float*)d_in[2];
    const int* mask = (const int*)d_in[3];
    const float* Wq = (const float*)d_in[4];
    const float* Wk = (const float*)d_in[5];
    const float* Wv = (const float*)d_in[6];
    const float* Wo = (const float*)d_in[7];
    float* out = (float*)d_out;

    char* ws = (char*)d_ws;
    size_t off = 0;
    auto alloc = [&](size_t bytes) {
        void* p = ws + off;
        off += (bytes + 255) & ~(size_t)255;
        return p;
    };
    const size_t MAT = (size_t)MROWS * DM * 2;      // 6291456 B
    const size_t WMAT = (size_t)DM * DM * 2;        // 1179648 B
    // Layout: WoT | qh kh vhT | pmask | lsb | [WqT WkT WvT ... pob overlays here]
    // ao overlays qh (dead after attn; merge runs after attn in-stream).
    unsigned short* WoT = (unsigned short*)alloc(WMAT);
    unsigned short* qh  = (unsigned short*)alloc(MAT);
    unsigned short* kh  = (unsigned short*)alloc(MAT);
    unsigned short* vhT = (unsigned short*)alloc(MAT);
    uint32_t* pmask     = (uint32_t*)alloc((size_t)NB * S_LEN * 64 * 4);
    float* lsb          = (float*)alloc((size_t)8 * NH * S_LEN * 4);
    unsigned short* WqT = (unsigned short*)alloc(WMAT);
    unsigned short* WkT = (unsigned short*)alloc(WMAT);
    unsigned short* WvT = (unsigned short*)alloc(WMAT);
    unsigned short* pob = WqT;  // overlays WqT/WkT/WvT + extends (dead after proj_gemm)
    (void)alloc((size_t)8 * S_LEN * DM * 2 - 3 * WMAT);  // reserve pob tail
    unsigned short* ao = qh;    // overlays qh (dead after attn)

    prep_kernel<<<dim3(576 + 4096), 256, 0, stream>>>(Wq, Wk, Wv, Wo, mask,
                                                      WqT, WkT, WvT, WoT, pmask);
    proj_gemm<<<dim3(576), 256, 0, stream>>>(q, k, v, WqT, WkT, WvT, qh, kh, vhT);
    attn_kernel<<<dim3(1536), 256, 0, stream>>>(qh, kh, vhT, pmask, pob, lsb);
    merge_kernel<<<dim3(3072), 256, 0, stream>>>(pob, lsb, ao);
    out_gemm<<<dim3(768), 256, 0, stream>>>(ao, WoT, out);
}